// Round 11
// baseline (277.538 us; speedup 1.0000x reference)
//
#include <hip/hip_runtime.h>
#include <hip/hip_fp16.h>

#define EPS 1e-5f
#define NREP 16       // colsum/sumsq replicas (breaks the R8/R9 atomic storm)
#define REPSTRIDE 132 // floats per replica row; staggers L2 lines

// ---------------------------------------------------------------------------
// K1: in-degree histogram (edges only; self-loop folded in as +1 later)
__global__ void count_kernel(const int* __restrict__ col, int* __restrict__ counts, int E) {
    int e = blockIdx.x * blockDim.x + threadIdx.x;
    if (e < E) atomicAdd(&counts[col[e]], 1);
}

// ---------------------------------------------------------------------------
// K2a: per-block (256 counts each) partial sums
__global__ void scan_reduce(const int* __restrict__ counts, int* __restrict__ blockSums, int N) {
    __shared__ int red[256];
    int i = blockIdx.x * 256 + threadIdx.x;
    red[threadIdx.x] = (i < N) ? counts[i] : 0;
    __syncthreads();
    for (int d = 128; d > 0; d >>= 1) {
        if (threadIdx.x < d) red[threadIdx.x] += red[threadIdx.x + d];
        __syncthreads();
    }
    if (threadIdx.x == 0) blockSums[blockIdx.x] = red[0];
}

// K2b (merged): each block derives its own global prefix by REDUCING
// blockSums[0..bid) (<=4 loads/thread), then scans its 256 counts.
// Removes the serial scan_blocksums dispatch (R10: one less launch+gap).
__global__ void scan_apply(const int* __restrict__ counts, const int* __restrict__ blockSums,
                           int nb, int* __restrict__ offsets, float* __restrict__ dinv, int N) {
    __shared__ int red[256];
    __shared__ int s[256];
    int tid = threadIdx.x, bid = blockIdx.x;
    // prefix over preceding block sums (reduction, wave-friendly)
    int local = 0;
    for (int j = tid; j < bid; j += 256) local += blockSums[j];
    red[tid] = local;
    __syncthreads();
    for (int d = 128; d > 0; d >>= 1) {
        if (tid < d) red[tid] += red[tid + d];
        __syncthreads();
    }
    int blockOff = red[0];
    // in-block inclusive scan of counts
    int i = bid * 256 + tid;
    int c = (i < N) ? counts[i] : 0;
    s[tid] = c;
    __syncthreads();
    for (int d = 1; d < 256; d <<= 1) {
        int v = (tid >= d) ? s[tid - d] : 0;
        __syncthreads();
        s[tid] += v;
        __syncthreads();
    }
    if (i < N) {
        offsets[i] = blockOff + s[tid] - c;   // exclusive
        dinv[i] = rsqrtf((float)(c + 1));     // +1 self loop; deg >= 1
    }
    if (bid == nb - 1 && tid == 255) offsets[N] = blockOff + s[255];
}

// ---------------------------------------------------------------------------
// K3: scatter edge sources into CSR buckets
__global__ void scatter_kernel(const int* __restrict__ row, const int* __restrict__ col,
                               const int* __restrict__ offsets, int* __restrict__ cursor,
                               int* __restrict__ csr, int E) {
    int e = blockIdx.x * blockDim.x + threadIdx.x;
    if (e < E) {
        int c = col[e];
        int pos = offsets[c] + atomicAdd(&cursor[c], 1);
        csr[pos] = row[e];
    }
}

// ---------------------------------------------------------------------------
// K4: xs = fp16( (x @ W.T) * dinv[row] )  — W-resident, 128 rows x 64 COLS/block.
// R10 post-mortem: 391 blocks / 256 CUs = 1.53 blocks/CU imbalance, occupancy
// 14%, gemm stuck at 54us. Fix: halve COLUMNS per block (not rows — R5 showed
// 4-col x 4-row tiles hit 1.5x the LDS pipe): 64-col W tile = 32 KB LDS, 2
// cols x 8 rows/thread keeps LDS demand at 0.75 of the pipe, 782 blocks =
// 3.05/CU and 3 blocks/CU resident. x re-read 2x (51 MB, L3-hot) is cheap.
// launch_bounds(512,2) = 128-VGPR budget (R6: (512,4) => 64-cap => 650 MB spill).
__global__ __launch_bounds__(512, 2) void gemm_kernel(
    const float* __restrict__ x, const float* __restrict__ W,
    const float* __restrict__ dinv, __half* __restrict__ xsh, int N) {
    __shared__ float sw[64 * 128];  // 32 KB, elem (jl,k) at jl*128 + (k ^ ((jl&31)<<2))
    int tid = threadIdx.x;
    int c  = tid & 31;   // column lane: local cols c, c+32
    int rg = tid >> 5;   // row group in [0,16): rows rg + 16i, i in [0,8)
    int r0 = (blockIdx.x >> 1) * 128;
    int c0 = (blockIdx.x & 1) * 64;

    // stage 64 W rows: 2048 float4s, 4 per thread
#pragma unroll
    for (int t = 0; t < 4; ++t) {
        int idx = tid + t * 512;                   // [0,2048)
        int jl = idx >> 5, k4 = idx & 31;          // jl in [0,64), k4 in [0,32)
        float4 v = ((const float4*)W)[(c0 + jl) * 32 + k4];
        *((float4*)&sw[jl * 128 + ((k4 * 4) ^ ((jl & 31) << 2))]) = v;
    }
    __syncthreads();

    int cswz = c << 2;

    const float4* xr[8];
    bool valid[8];
#pragma unroll
    for (int i = 0; i < 8; ++i) {
        int grow = r0 + rg + 16 * i;
        valid[i] = (grow < N);
        xr[i] = (const float4*)&x[(size_t)(valid[i] ? grow : 0) * 128];
    }

    float acc[8][2];
#pragma unroll
    for (int i = 0; i < 8; ++i) { acc[i][0] = 0.f; acc[i][1] = 0.f; }

#pragma unroll 4
    for (int k4 = 0; k4 < 32; ++k4) {
        float4 wv[2], xv[8];
#pragma unroll
        for (int q = 0; q < 2; ++q)
            wv[q] = *((const float4*)&sw[(c + 32 * q) * 128 + ((k4 * 4) ^ cswz)]);
#pragma unroll
        for (int i = 0; i < 8; ++i) xv[i] = xr[i][k4];
#pragma unroll
        for (int i = 0; i < 8; ++i)
#pragma unroll
            for (int q = 0; q < 2; ++q)
                acc[i][q] += xv[i].x * wv[q].x + xv[i].y * wv[q].y +
                             xv[i].z * wv[q].z + xv[i].w * wv[q].w;
    }

#pragma unroll
    for (int i = 0; i < 8; ++i) {
        int grow = r0 + rg + 16 * i;
        if (valid[i]) {
            float dv = dinv[grow];
#pragma unroll
            for (int q = 0; q < 2; ++q)
                xsh[(size_t)grow * 128 + c0 + c + 32 * q] = __float2half(acc[i][q] * dv);
        }
    }
}

// ---------------------------------------------------------------------------
// K5: gather + fused moments (replicated accumulators), TWO NODES PER WAVE.
// R10 diagnosis: 52us at 51% occupancy, 17% VALU, 66 MB FETCH -> latency-
// bound on per-node load chains (deg-12 node = 3 serial wait windows). Fix:
// each wave owns node pair (2w, 2w+1) and interleaves their batches -> 2x
// loads in flight per wait window. All branches are wave-uniform (degree-
// based scalar compares) — no per-lane predication (R8 lesson).
__global__ void gather_kernel(const __half2* __restrict__ xs2, const float* __restrict__ dinv,
                              const int* __restrict__ offsets, const int* __restrict__ csr,
                              float* __restrict__ pre, float* __restrict__ colrep,
                              float* __restrict__ ssrep, int N) {
    __shared__ float scol[128];
    __shared__ float sss;
    if (threadIdx.x < 128) scol[threadIdx.x] = 0.f;
    if (threadIdx.x == 0) sss = 0.f;
    __syncthreads();

    int lane = threadIdx.x & 63;
    int wid = (blockIdx.x * blockDim.x + threadIdx.x) >> 6;
    int nw  = (gridDim.x * blockDim.x) >> 6;
    float2* pre2 = (float2*)pre;
    float csx = 0.f, csy = 0.f, ss = 0.f;

    for (int base = wid * 2; base < N; base += nw * 2) {
        int n0 = base, n1 = base + 1;
        bool has1 = (n1 < N);
        int s0 = offsets[n0], e0 = offsets[n0 + 1];
        int s1 = 0, e1 = 0;
        if (has1) { s1 = offsets[n1]; e1 = offsets[n1 + 1]; }
        float2 acc0 = __half22float2(xs2[(size_t)n0 * 64 + lane]);
        float2 acc1 = make_float2(0.f, 0.f);
        if (has1) acc1 = __half22float2(xs2[(size_t)n1 * 64 + lane]);
        int p0 = s0, p1 = s1;

        // joint 8+8: 16 gathers in flight
        while (p0 + 8 <= e0 && p1 + 8 <= e1) {
            int i0[8], i1[8];
#pragma unroll
            for (int t = 0; t < 8; ++t) { i0[t] = csr[p0 + t]; i1[t] = csr[p1 + t]; }
            __half2 a0[8], a1[8];
#pragma unroll
            for (int t = 0; t < 8; ++t) { a0[t] = xs2[(size_t)i0[t] * 64 + lane];
                                          a1[t] = xs2[(size_t)i1[t] * 64 + lane]; }
#pragma unroll
            for (int t = 0; t < 8; ++t) {
                float2 f0 = __half22float2(a0[t]), f1 = __half22float2(a1[t]);
                acc0.x += f0.x; acc0.y += f0.y; acc1.x += f1.x; acc1.y += f1.y;
            }
            p0 += 8; p1 += 8;
        }
        // drain 8-batches individually
        while (p0 + 8 <= e0) {
            int idx[8];
#pragma unroll
            for (int t = 0; t < 8; ++t) idx[t] = csr[p0 + t];
            __half2 a[8];
#pragma unroll
            for (int t = 0; t < 8; ++t) a[t] = xs2[(size_t)idx[t] * 64 + lane];
#pragma unroll
            for (int t = 0; t < 8; ++t) { float2 f = __half22float2(a[t]);
                                          acc0.x += f.x; acc0.y += f.y; }
            p0 += 8;
        }
        while (p1 + 8 <= e1) {
            int idx[8];
#pragma unroll
            for (int t = 0; t < 8; ++t) idx[t] = csr[p1 + t];
            __half2 a[8];
#pragma unroll
            for (int t = 0; t < 8; ++t) a[t] = xs2[(size_t)idx[t] * 64 + lane];
#pragma unroll
            for (int t = 0; t < 8; ++t) { float2 f = __half22float2(a[t]);
                                          acc1.x += f.x; acc1.y += f.y; }
            p1 += 8;
        }
        // joint 4+4
        if (p0 + 4 <= e0 && p1 + 4 <= e1) {
            int i0[4], i1[4];
#pragma unroll
            for (int t = 0; t < 4; ++t) { i0[t] = csr[p0 + t]; i1[t] = csr[p1 + t]; }
            __half2 a0[4], a1[4];
#pragma unroll
            for (int t = 0; t < 4; ++t) { a0[t] = xs2[(size_t)i0[t] * 64 + lane];
                                          a1[t] = xs2[(size_t)i1[t] * 64 + lane]; }
#pragma unroll
            for (int t = 0; t < 4; ++t) {
                float2 f0 = __half22float2(a0[t]), f1 = __half22float2(a1[t]);
                acc0.x += f0.x; acc0.y += f0.y; acc1.x += f1.x; acc1.y += f1.y;
            }
            p0 += 4; p1 += 4;
        }
        if (p0 + 4 <= e0) {
            int idx[4];
#pragma unroll
            for (int t = 0; t < 4; ++t) idx[t] = csr[p0 + t];
            __half2 a[4];
#pragma unroll
            for (int t = 0; t < 4; ++t) a[t] = xs2[(size_t)idx[t] * 64 + lane];
#pragma unroll
            for (int t = 0; t < 4; ++t) { float2 f = __half22float2(a[t]);
                                          acc0.x += f.x; acc0.y += f.y; }
            p0 += 4;
        }
        if (p1 + 4 <= e1) {
            int idx[4];
#pragma unroll
            for (int t = 0; t < 4; ++t) idx[t] = csr[p1 + t];
            __half2 a[4];
#pragma unroll
            for (int t = 0; t < 4; ++t) a[t] = xs2[(size_t)idx[t] * 64 + lane];
#pragma unroll
            for (int t = 0; t < 4; ++t) { float2 f = __half22float2(a[t]);
                                          acc1.x += f.x; acc1.y += f.y; }
            p1 += 4;
        }
        // joint scalars
        while (p0 < e0 && p1 < e1) {
            __half2 a0 = xs2[(size_t)csr[p0] * 64 + lane];
            __half2 a1 = xs2[(size_t)csr[p1] * 64 + lane];
            float2 f0 = __half22float2(a0), f1 = __half22float2(a1);
            acc0.x += f0.x; acc0.y += f0.y; acc1.x += f1.x; acc1.y += f1.y;
            ++p0; ++p1;
        }
        for (; p0 < e0; ++p0) {
            float2 f = __half22float2(xs2[(size_t)csr[p0] * 64 + lane]);
            acc0.x += f.x; acc0.y += f.y;
        }
        for (; p1 < e1; ++p1) {
            float2 f = __half22float2(xs2[(size_t)csr[p1] * 64 + lane]);
            acc1.x += f.x; acc1.y += f.y;
        }

        float dv0 = dinv[n0];
        float vx = acc0.x * dv0, vy = acc0.y * dv0;
        pre2[(size_t)n0 * 64 + lane] = make_float2(vx, vy);
        csx += vx; csy += vy; ss += vx * vx + vy * vy;
        if (has1) {
            float dv1 = dinv[n1];
            float wx = acc1.x * dv1, wy = acc1.y * dv1;
            pre2[(size_t)n1 * 64 + lane] = make_float2(wx, wy);
            csx += wx; csy += wy; ss += wx * wx + wy * wy;
        }
    }

    // block-level reduction, then one atomic per slot into replica blockIdx&15
    atomicAdd(&scol[2 * lane], csx);
    atomicAdd(&scol[2 * lane + 1], csy);
    for (int d = 32; d > 0; d >>= 1) ss += __shfl_down(ss, d);
    if (lane == 0) atomicAdd(&sss, ss);
    __syncthreads();
    int rep = blockIdx.x & (NREP - 1);
    if (threadIdx.x < 128) atomicAdd(&colrep[rep * REPSTRIDE + threadIdx.x], scol[threadIdx.x]);
    if (threadIdx.x == 128) atomicAdd(&ssrep[rep], sss);
}

// ---------------------------------------------------------------------------
// K8: FUSED params + apply. Each block sums the 16 replicas to derive m[j]
// and s (all L2-hot), then: y=(v-m_j)*s; out = y>0 ? 2y : y.
__global__ void final_kernel(float* __restrict__ out, const float* __restrict__ colrep,
                             const float* __restrict__ ssrep, int N, int total) {
    __shared__ float sm[128];
    __shared__ float red[128];
    __shared__ float sscale;
    int t = threadIdx.x;
    if (t < 128) {
        float cs = 0.f;
#pragma unroll
        for (int r = 0; r < NREP; ++r) cs += colrep[r * REPSTRIDE + t];
        float m = cs / (float)N;
        sm[t] = m;
        red[t] = m * m;
    }
    __syncthreads();
    for (int d = 64; d > 0; d >>= 1) {
        if (t < d) red[t] += red[t + d];
        __syncthreads();
    }
    if (t == 0) {
        float sq = 0.f;
#pragma unroll
        for (int r = 0; r < NREP; ++r) sq += ssrep[r];
        float tot = sq - (float)N * red[0];  // sum (out - m)^2
        sscale = rsqrtf(EPS + tot / (float)N);
    }
    __syncthreads();
    float s = sscale;
    int tid = blockIdx.x * blockDim.x + threadIdx.x;
    int stride = gridDim.x * blockDim.x;
    for (int i = tid; i < total; i += stride) {
        float y = (out[i] - sm[i & 127]) * s;
        out[i] = y > 0.f ? 2.f * y : y;
    }
}

// ---------------------------------------------------------------------------
extern "C" void kernel_launch(void* const* d_in, const int* in_sizes, int n_in,
                              void* d_out, int out_size, void* d_ws, size_t ws_size,
                              hipStream_t stream) {
    const float* x = (const float*)d_in[0];
    const float* W = (const float*)d_in[1];
    const int* ei  = (const int*)d_in[2];
    int N = in_sizes[0] / 128;
    int E = in_sizes[2] / 2;
    const int* row = ei;        // edge_index[0] = source
    const int* col = ei + E;    // edge_index[1] = aggregation target
    float* out = (float*)d_out;

    int nb = (N + 255) / 256;   // scan blocks (196 for N=50000; must be <= 1024)

    // workspace layout (xs is fp16 = N*64 float-slots; rest 4-byte elements)
    __half* xsh      = (__half*)d_ws;                  // N*128 halves
    float* dinv      = (float*)d_ws + (size_t)N * 64;  // N
    int*   counts    = (int*)(dinv + N);               // N              [zeroed]
    int*   cursor    = counts + N;                     // N              [zeroed]
    float* colrep    = (float*)(cursor + N);           // NREP*REPSTRIDE [zeroed]
    float* ssrep     = colrep + NREP * REPSTRIDE;      // NREP           [zeroed]
    int*   offsets   = (int*)(ssrep + NREP);           // N+1
    int*   csr       = offsets + (N + 1);              // E
    int*   blockSums = csr + E;                        // nb

    hipMemsetAsync(counts, 0, (size_t)(2 * N + NREP * REPSTRIDE + NREP) * 4, stream);

    count_kernel  <<<(E + 255) / 256, 256, 0, stream>>>(col, counts, E);
    scan_reduce   <<<nb, 256, 0, stream>>>(counts, blockSums, N);
    scan_apply    <<<nb, 256, 0, stream>>>(counts, blockSums, nb, offsets, dinv, N);
    scatter_kernel<<<(E + 255) / 256, 256, 0, stream>>>(row, col, offsets, cursor, csr, E);
    gemm_kernel   <<<2 * ((N + 127) / 128), 512, 0, stream>>>(x, W, dinv, xsh, N);
    gather_kernel <<<2048, 256, 0, stream>>>((const __half2*)xsh, dinv, offsets, csr,
                                             out, colrep, ssrep, N);
    final_kernel  <<<1024, 256, 0, stream>>>(out, colrep, ssrep, N, N * 128);
}